// Round 1
// baseline (1595.103 us; speedup 1.0000x reference)
//
#include <hip/hip_runtime.h>

#define N_NODES 100000
#define N_EDGES 1600000
#define D 128

// deg[c] = number of incoming edges (self loop added later as +1)
__global__ __launch_bounds__(256) void k_degree(const int* __restrict__ col,
                                                int* __restrict__ deg) {
    int e = blockIdx.x * 256 + threadIdx.x;
    if (e < N_EDGES) atomicAdd(&deg[col[e]], 1);
}

__global__ __launch_bounds__(256) void k_dis(const int* __restrict__ deg,
                                             float* __restrict__ dis) {
    int n = blockIdx.x * 256 + threadIdx.x;
    if (n < N_NODES) dis[n] = rsqrtf((float)deg[n] + 1.0f);
}

// One wave (64 lanes) per edge; float2 per lane covers D=128.
// agg[col] += x[row] * (dis[row]*dis[col]), accumulated into d_out (pre-zeroed).
__global__ __launch_bounds__(256) void k_scatter(const int* __restrict__ row,
                                                 const int* __restrict__ col,
                                                 const float* __restrict__ x,
                                                 const float* __restrict__ dis,
                                                 float* __restrict__ out) {
    int wid = (blockIdx.x * 256 + threadIdx.x) >> 6;
    int lane = threadIdx.x & 63;
    if (wid >= N_EDGES) return;
    int r = row[wid];
    int c = col[wid];
    float norm = dis[r] * dis[c];
    float2 v = ((const float2*)(x + (size_t)r * D))[lane];
    float* o = out + (size_t)c * D + lane * 2;
    unsafeAtomicAdd(o, v.x * norm);
    unsafeAtomicAdd(o + 1, v.y * norm);
}

// In-place: out_row = relu((agg_row + x_row*dis^2) @ W^T + bias).
// Block owns 32 full rows: stages them into LDS BEFORE any write (race-free
// aliasing), W staged in two 64-row halves (full padded W > 64 KB static LDS).
__global__ __launch_bounds__(256) void k_transform(const float* __restrict__ x,
                                                   const float* __restrict__ w,
                                                   const float* __restrict__ bias,
                                                   const float* __restrict__ dis,
                                                   float* __restrict__ out) {
    __shared__ float Wl[64 * 132];   // 33792 B, pad 132 keeps 16B align + no conflicts
    __shared__ float Vl[32 * 128];   // 16384 B
    __shared__ float Bl[128];
    int t = threadIdx.x;
    int row0 = blockIdx.x * 32;

    // stage 32 rows of agg + self-loop contribution
    for (int i = t; i < 32 * 128; i += 256) {
        int rr = i >> 7;
        int node = row0 + rr;
        float dsn = dis[node];
        size_t off = (size_t)node * D + (i & 127);
        Vl[i] = out[off] + x[off] * (dsn * dsn);
    }
    if (t < 128) Bl[t] = bias[t];

    int jl = t & 63;          // local output column within the half
    int r0 = t >> 6;          // 4 rows in flight per iteration
    for (int half = 0; half < 2; ++half) {
        __syncthreads();      // Vl ready / previous half's Wl reads done
        for (int i = t; i < 64 * 128; i += 256) {
            int jj = i >> 7, k = i & 127;
            Wl[jj * 132 + k] = w[((half * 64 + jj) << 7) + k];
        }
        __syncthreads();
        int j = half * 64 + jl;
        const float4* wp = (const float4*)(Wl + jl * 132);
        float bj = Bl[j];
        for (int rb = 0; rb < 32; rb += 4) {
            int rr = rb + r0;
            const float4* vp = (const float4*)(Vl + rr * 128);
            float4 a4 = {0.f, 0.f, 0.f, 0.f};
            #pragma unroll 8
            for (int k4 = 0; k4 < 32; ++k4) {
                float4 vv = vp[k4];
                float4 ww = wp[k4];
                a4.x += vv.x * ww.x;
                a4.y += vv.y * ww.y;
                a4.z += vv.z * ww.z;
                a4.w += vv.w * ww.w;
            }
            float acc = (a4.x + a4.y) + (a4.z + a4.w) + bj;
            out[(size_t)(row0 + rr) * D + j] = fmaxf(acc, 0.f);
        }
    }
}

extern "C" void kernel_launch(void* const* d_in, const int* in_sizes, int n_in,
                              void* d_out, int out_size, void* d_ws, size_t ws_size,
                              hipStream_t stream) {
    const float* x    = (const float*)d_in[0];
    const int*   ei   = (const int*)d_in[1];    // [2, E]: row then col
    const float* w    = (const float*)d_in[2];
    const float* bias = (const float*)d_in[3];
    float* out = (float*)d_out;

    int*   deg = (int*)d_ws;
    float* dis = (float*)((char*)d_ws + N_NODES * sizeof(int));
    const int* row = ei;
    const int* col = ei + N_EDGES;

    // d_out doubles as the aggregation buffer; ws/out are poisoned each call.
    hipMemsetAsync(d_out, 0, (size_t)N_NODES * D * sizeof(float), stream);
    hipMemsetAsync(d_ws, 0, N_NODES * sizeof(int), stream);

    k_degree<<<(N_EDGES + 255) / 256, 256, 0, stream>>>(col, deg);
    k_dis<<<(N_NODES + 255) / 256, 256, 0, stream>>>(deg, dis);
    k_scatter<<<N_EDGES / 4, 256, 0, stream>>>(row, col, x, dis, out);
    k_transform<<<N_NODES / 32, 256, 0, stream>>>(x, w, bias, dis, out);
}

// Round 2
// 592.672 us; speedup vs baseline: 2.6914x; 2.6914x over previous
//
#include <hip/hip_runtime.h>

#define N_NODES 100000
#define N_EDGES 1600000
#define D 128
#define NBLK_SCAN ((N_NODES + 255) / 256)   // 391

// ---- pass 1: in-degree (self loop accounted as +1 inside k_dis) ----
__global__ __launch_bounds__(256) void k_degree(const int* __restrict__ col,
                                                int* __restrict__ deg) {
    int e = blockIdx.x * 256 + threadIdx.x;
    if (e < N_EDGES) atomicAdd(&deg[col[e]], 1);
}

__global__ __launch_bounds__(256) void k_dis(const int* __restrict__ deg,
                                             float* __restrict__ dis) {
    int n = blockIdx.x * 256 + threadIdx.x;
    if (n < N_NODES) dis[n] = rsqrtf((float)deg[n] + 1.0f);
}

// ---- exclusive scan of deg -> start (3 kernels, hierarchical) ----
__global__ __launch_bounds__(256) void k_scan1(const int* __restrict__ deg,
                                               int* __restrict__ start,
                                               int* __restrict__ sums) {
    __shared__ int buf[256];
    int i = blockIdx.x * 256 + threadIdx.x;
    int v = (i < N_NODES) ? deg[i] : 0;
    buf[threadIdx.x] = v;
    __syncthreads();
    for (int off = 1; off < 256; off <<= 1) {
        int t = (threadIdx.x >= off) ? buf[threadIdx.x - off] : 0;
        __syncthreads();
        buf[threadIdx.x] += t;
        __syncthreads();
    }
    if (i < N_NODES) start[i] = buf[threadIdx.x] - v;   // exclusive
    if (threadIdx.x == 255) sums[blockIdx.x] = buf[255];
}

__global__ void k_scan2(int* __restrict__ sums) {
    if (threadIdx.x == 0) {
        int acc = 0;
        for (int b = 0; b < NBLK_SCAN; ++b) { int v = sums[b]; sums[b] = acc; acc += v; }
    }
}

__global__ __launch_bounds__(256) void k_scan3(int* __restrict__ start,
                                               int* __restrict__ cursor,
                                               const int* __restrict__ sums) {
    int i = blockIdx.x * 256 + threadIdx.x;
    if (i < N_NODES) {
        int s = start[i] + sums[blockIdx.x];
        start[i] = s;
        cursor[i] = s;
    }
}

// ---- pass 2: bucket edges by destination (counting sort) ----
__global__ __launch_bounds__(256) void k_bucket(const int* __restrict__ row,
                                                const int* __restrict__ col,
                                                int* __restrict__ cursor,
                                                int* __restrict__ srcs) {
    int e = blockIdx.x * 256 + threadIdx.x;
    if (e < N_EDGES) {
        int c = col[e];
        int pos = atomicAdd(&cursor[c], 1);
        srcs[pos] = row[e];
    }
}

// ---- pass 3: gather-aggregate, one wave per destination node ----
// acc = sum_{src in bucket} x[src] * dis[src]*dis[node]  +  x[node]*dis[node]^2
// Each lane holds float2 (64 lanes * 8B = 512B = one full row, coalesced).
// Single non-atomic write per output element.
__global__ __launch_bounds__(256) void k_aggregate(const int* __restrict__ srcs,
                                                   const int* __restrict__ start,
                                                   const int* __restrict__ deg,
                                                   const float* __restrict__ x,
                                                   const float* __restrict__ dis,
                                                   float* __restrict__ out) {
    int node = (blockIdx.x * 256 + threadIdx.x) >> 6;
    int lane = threadIdx.x & 63;
    if (node >= N_NODES) return;
    int s = start[node];
    int n = deg[node];
    float dc = dis[node];
    // self loop
    float2 v0 = ((const float2*)(x + (size_t)node * D))[lane];
    float2 acc;
    acc.x = v0.x * dc * dc;
    acc.y = v0.y * dc * dc;
    for (int i = 0; i < n; ++i) {
        int src = srcs[s + i];
        float nr = dis[src] * dc;
        float2 v = ((const float2*)(x + (size_t)src * D))[lane];
        acc.x += v.x * nr;
        acc.y += v.y * nr;
    }
    ((float2*)(out + (size_t)node * D))[lane] = acc;
}

// ---- pass 4: in-place out = relu(out @ W^T + bias) ----
// Block owns 32 full rows: stages them into LDS BEFORE any write (race-free
// in-place), W staged in two 64-row halves (full padded W > 64 KB static LDS).
__global__ __launch_bounds__(256) void k_transform(const float* __restrict__ w,
                                                   const float* __restrict__ bias,
                                                   float* __restrict__ out) {
    __shared__ float Wl[64 * 132];   // pad 132: 16B-aligned rows, no conflicts
    __shared__ float Vl[32 * 128];
    __shared__ float Bl[128];
    int t = threadIdx.x;
    int row0 = blockIdx.x * 32;

    for (int i = t; i < 32 * 128; i += 256)
        Vl[i] = out[(size_t)row0 * D + i];
    if (t < 128) Bl[t] = bias[t];

    int jl = t & 63;
    int r0 = t >> 6;
    for (int half = 0; half < 2; ++half) {
        __syncthreads();
        for (int i = t; i < 64 * 128; i += 256) {
            int jj = i >> 7, k = i & 127;
            Wl[jj * 132 + k] = w[((half * 64 + jj) << 7) + k];
        }
        __syncthreads();
        int j = half * 64 + jl;
        const float4* wp = (const float4*)(Wl + jl * 132);
        float bj = Bl[j];
        for (int rb = 0; rb < 32; rb += 4) {
            int rr = rb + r0;
            const float4* vp = (const float4*)(Vl + rr * 128);
            float4 a4 = {0.f, 0.f, 0.f, 0.f};
            #pragma unroll 8
            for (int k4 = 0; k4 < 32; ++k4) {
                float4 vv = vp[k4];
                float4 ww = wp[k4];
                a4.x += vv.x * ww.x;
                a4.y += vv.y * ww.y;
                a4.z += vv.z * ww.z;
                a4.w += vv.w * ww.w;
            }
            float acc = (a4.x + a4.y) + (a4.z + a4.w) + bj;
            out[(size_t)(row0 + rr) * D + j] = fmaxf(acc, 0.f);
        }
    }
}

extern "C" void kernel_launch(void* const* d_in, const int* in_sizes, int n_in,
                              void* d_out, int out_size, void* d_ws, size_t ws_size,
                              hipStream_t stream) {
    const float* x    = (const float*)d_in[0];
    const int*   ei   = (const int*)d_in[1];    // [2, E]: row then col
    const float* w    = (const float*)d_in[2];
    const float* bias = (const float*)d_in[3];
    float* out = (float*)d_out;

    char* ws = (char*)d_ws;
    int*   deg    = (int*)ws;                 ws += N_NODES * 4;
    float* dis    = (float*)ws;               ws += N_NODES * 4;
    int*   start  = (int*)ws;                 ws += N_NODES * 4;
    int*   cursor = (int*)ws;                 ws += N_NODES * 4;
    int*   sums   = (int*)ws;                 ws += ((NBLK_SCAN + 127) & ~127) * 4;
    int*   srcs   = (int*)ws;                 // N_EDGES ints

    const int* row = ei;
    const int* col = ei + N_EDGES;

    hipMemsetAsync(deg, 0, N_NODES * sizeof(int), stream);

    k_degree   <<<(N_EDGES + 255) / 256, 256, 0, stream>>>(col, deg);
    k_dis      <<<NBLK_SCAN, 256, 0, stream>>>(deg, dis);
    k_scan1    <<<NBLK_SCAN, 256, 0, stream>>>(deg, start, sums);
    k_scan2    <<<1, 64, 0, stream>>>(sums);
    k_scan3    <<<NBLK_SCAN, 256, 0, stream>>>(start, cursor, sums);
    k_bucket   <<<(N_EDGES + 255) / 256, 256, 0, stream>>>(row, col, cursor, srcs);
    k_aggregate<<<(N_NODES * 64 + 255) / 256, 256, 0, stream>>>(srcs, start, deg, x, dis, out);
    k_transform<<<N_NODES / 32, 256, 0, stream>>>(w, bias, out);
}

// Round 3
// 529.521 us; speedup vs baseline: 3.0123x; 1.1193x over previous
//
#include <hip/hip_runtime.h>

#define N_NODES 100000
#define N_EDGES 1600000
#define D 128
#define NBLK_SCAN ((N_NODES + 255) / 256)   // 391

// ---- pass 1: in-degree (self loop accounted as +1 where consumed) ----
__global__ __launch_bounds__(256) void k_degree(const int* __restrict__ col,
                                                int* __restrict__ deg) {
    int e = blockIdx.x * 256 + threadIdx.x;
    if (e < N_EDGES) atomicAdd(&deg[col[e]], 1);
}

// ---- exclusive scan of deg -> start (3 kernels, hierarchical) ----
__global__ __launch_bounds__(256) void k_scan1(const int* __restrict__ deg,
                                               int* __restrict__ start,
                                               int* __restrict__ sums) {
    __shared__ int buf[256];
    int i = blockIdx.x * 256 + threadIdx.x;
    int v = (i < N_NODES) ? deg[i] : 0;
    buf[threadIdx.x] = v;
    __syncthreads();
    for (int off = 1; off < 256; off <<= 1) {
        int t = (threadIdx.x >= off) ? buf[threadIdx.x - off] : 0;
        __syncthreads();
        buf[threadIdx.x] += t;
        __syncthreads();
    }
    if (i < N_NODES) start[i] = buf[threadIdx.x] - v;   // exclusive
    if (threadIdx.x == 255) sums[blockIdx.x] = buf[255];
}

// single-block parallel exclusive scan of the 391 block sums (was: 1 serial thread)
__global__ __launch_bounds__(512) void k_scan2(int* __restrict__ sums) {
    __shared__ int buf[512];
    int t = threadIdx.x;
    int v = (t < NBLK_SCAN) ? sums[t] : 0;
    buf[t] = v;
    __syncthreads();
    for (int off = 1; off < 512; off <<= 1) {
        int u = (t >= off) ? buf[t - off] : 0;
        __syncthreads();
        buf[t] += u;
        __syncthreads();
    }
    if (t < NBLK_SCAN) sums[t] = buf[t] - v;   // exclusive
}

// finalize start, init cursor, and compute dis = rsqrt(deg+1) (fused)
__global__ __launch_bounds__(256) void k_scan3(int* __restrict__ start,
                                               int* __restrict__ cursor,
                                               const int* __restrict__ sums,
                                               const int* __restrict__ deg,
                                               float* __restrict__ dis) {
    int i = blockIdx.x * 256 + threadIdx.x;
    if (i < N_NODES) {
        int s = start[i] + sums[blockIdx.x];
        start[i] = s;
        cursor[i] = s;
        dis[i] = rsqrtf((float)deg[i] + 1.0f);
    }
}

// ---- pass 2: bucket edges by destination (counting sort) ----
__global__ __launch_bounds__(256) void k_bucket(const int* __restrict__ row,
                                                const int* __restrict__ col,
                                                int* __restrict__ cursor,
                                                int* __restrict__ srcs) {
    int e = blockIdx.x * 256 + threadIdx.x;
    if (e < N_EDGES) {
        int c = col[e];
        int pos = atomicAdd(&cursor[c], 1);
        srcs[pos] = row[e];
    }
}

// ---- pass 3: gather-aggregate, one wave per destination node ----
// Lane-parallel prefetch of up to 64 (src, dis[src]) pairs, broadcast via
// __shfl, edge loop unrolled x4 so 4 independent x-row loads are in flight
// (breaks the srcs->dis->x serial chain that made R2 latency-bound).
__global__ __launch_bounds__(256) void k_aggregate(const int* __restrict__ srcs,
                                                   const int* __restrict__ start,
                                                   const int* __restrict__ deg,
                                                   const float* __restrict__ x,
                                                   const float* __restrict__ dis,
                                                   float* __restrict__ out) {
    int node = (blockIdx.x * 256 + threadIdx.x) >> 6;
    int lane = threadIdx.x & 63;
    if (node >= N_NODES) return;
    int s = start[node];
    int n = deg[node];
    float dc = dis[node];
    float2 v0 = ((const float2*)(x + (size_t)node * D))[lane];
    float accx = v0.x * dc * dc;
    float accy = v0.y * dc * dc;

    for (int base = 0; base < n; base += 64) {
        int m = n - base; if (m > 64) m = 64;
        int   src_l = 0;
        float nr_l  = 0.f;
        if (lane < m) {
            src_l = srcs[s + base + lane];
            nr_l  = dis[src_l] * dc;
        }
        int i = 0;
        for (; i + 4 <= m; i += 4) {
            int s0 = __shfl(src_l, i + 0);
            int s1 = __shfl(src_l, i + 1);
            int s2 = __shfl(src_l, i + 2);
            int s3 = __shfl(src_l, i + 3);
            float n0 = __shfl(nr_l, i + 0);
            float n1 = __shfl(nr_l, i + 1);
            float n2 = __shfl(nr_l, i + 2);
            float n3 = __shfl(nr_l, i + 3);
            float2 a0 = ((const float2*)(x + (size_t)s0 * D))[lane];
            float2 a1 = ((const float2*)(x + (size_t)s1 * D))[lane];
            float2 a2 = ((const float2*)(x + (size_t)s2 * D))[lane];
            float2 a3 = ((const float2*)(x + (size_t)s3 * D))[lane];
            accx += a0.x * n0; accy += a0.y * n0;
            accx += a1.x * n1; accy += a1.y * n1;
            accx += a2.x * n2; accy += a2.y * n2;
            accx += a3.x * n3; accy += a3.y * n3;
        }
        for (; i < m; ++i) {
            int   si = __shfl(src_l, i);
            float ni = __shfl(nr_l, i);
            float2 a = ((const float2*)(x + (size_t)si * D))[lane];
            accx += a.x * ni; accy += a.y * ni;
        }
    }
    float2 r; r.x = accx; r.y = accy;
    ((float2*)(out + (size_t)node * D))[lane] = r;
}

// ---- pass 4: in-place out = relu(out @ W^T + bias) ----
// Block owns 32 full rows: stages them into LDS BEFORE any write (race-free
// in-place), W staged in two 64-row halves.
__global__ __launch_bounds__(256) void k_transform(const float* __restrict__ w,
                                                   const float* __restrict__ bias,
                                                   float* __restrict__ out) {
    __shared__ float Wl[64 * 132];
    __shared__ float Vl[32 * 128];
    __shared__ float Bl[128];
    int t = threadIdx.x;
    int row0 = blockIdx.x * 32;

    for (int i = t; i < 32 * 128; i += 256)
        Vl[i] = out[(size_t)row0 * D + i];
    if (t < 128) Bl[t] = bias[t];

    int jl = t & 63;
    int r0 = t >> 6;
    for (int half = 0; half < 2; ++half) {
        __syncthreads();
        for (int i = t; i < 64 * 128; i += 256) {
            int jj = i >> 7, k = i & 127;
            Wl[jj * 132 + k] = w[((half * 64 + jj) << 7) + k];
        }
        __syncthreads();
        int j = half * 64 + jl;
        const float4* wp = (const float4*)(Wl + jl * 132);
        float bj = Bl[j];
        for (int rb = 0; rb < 32; rb += 4) {
            int rr = rb + r0;
            const float4* vp = (const float4*)(Vl + rr * 128);
            float4 a4 = {0.f, 0.f, 0.f, 0.f};
            #pragma unroll 8
            for (int k4 = 0; k4 < 32; ++k4) {
                float4 vv = vp[k4];
                float4 ww = wp[k4];
                a4.x += vv.x * ww.x;
                a4.y += vv.y * ww.y;
                a4.z += vv.z * ww.z;
                a4.w += vv.w * ww.w;
            }
            float acc = (a4.x + a4.y) + (a4.z + a4.w) + bj;
            out[(size_t)(row0 + rr) * D + j] = fmaxf(acc, 0.f);
        }
    }
}

extern "C" void kernel_launch(void* const* d_in, const int* in_sizes, int n_in,
                              void* d_out, int out_size, void* d_ws, size_t ws_size,
                              hipStream_t stream) {
    const float* x    = (const float*)d_in[0];
    const int*   ei   = (const int*)d_in[1];    // [2, E]: row then col
    const float* w    = (const float*)d_in[2];
    const float* bias = (const float*)d_in[3];
    float* out = (float*)d_out;

    char* ws = (char*)d_ws;
    int*   deg    = (int*)ws;                 ws += N_NODES * 4;
    float* dis    = (float*)ws;               ws += N_NODES * 4;
    int*   start  = (int*)ws;                 ws += N_NODES * 4;
    int*   cursor = (int*)ws;                 ws += N_NODES * 4;
    int*   sums   = (int*)ws;                 ws += ((NBLK_SCAN + 127) & ~127) * 4;
    int*   srcs   = (int*)ws;                 // N_EDGES ints

    const int* row = ei;
    const int* col = ei + N_EDGES;

    hipMemsetAsync(deg, 0, N_NODES * sizeof(int), stream);

    k_degree   <<<(N_EDGES + 255) / 256, 256, 0, stream>>>(col, deg);
    k_scan1    <<<NBLK_SCAN, 256, 0, stream>>>(deg, start, sums);
    k_scan2    <<<1, 512, 0, stream>>>(sums);
    k_scan3    <<<NBLK_SCAN, 256, 0, stream>>>(start, cursor, sums, deg, dis);
    k_bucket   <<<(N_EDGES + 255) / 256, 256, 0, stream>>>(row, col, cursor, srcs);
    k_aggregate<<<(N_NODES * 64 + 255) / 256, 256, 0, stream>>>(srcs, start, deg, x, dis, out);
    k_transform<<<N_NODES / 32, 256, 0, stream>>>(w, bias, out);
}

// Round 4
// 433.657 us; speedup vs baseline: 3.6783x; 1.2211x over previous
//
#include <hip/hip_runtime.h>

#define N_NODES 100000
#define N_EDGES 1600000
#define D 128
#define NBLK_SCAN ((N_NODES + 255) / 256)   // 391
#define N_STRIPS (N_NODES / 32)             // 3125 (N_NODES % 32 == 0)

typedef __bf16 bf16x8 __attribute__((ext_vector_type(8)));
typedef float  f32x4  __attribute__((ext_vector_type(4)));

// ---- pass 1: in-degree (self loop accounted as +1 where consumed) ----
__global__ __launch_bounds__(256) void k_degree(const int* __restrict__ col,
                                                int* __restrict__ deg) {
    int e = blockIdx.x * 256 + threadIdx.x;
    if (e < N_EDGES) atomicAdd(&deg[col[e]], 1);
}

// ---- exclusive scan of deg -> start ----
__global__ __launch_bounds__(256) void k_scan1(const int* __restrict__ deg,
                                               int* __restrict__ start,
                                               int* __restrict__ sums) {
    __shared__ int buf[256];
    int i = blockIdx.x * 256 + threadIdx.x;
    int v = (i < N_NODES) ? deg[i] : 0;
    buf[threadIdx.x] = v;
    __syncthreads();
    for (int off = 1; off < 256; off <<= 1) {
        int t = (threadIdx.x >= off) ? buf[threadIdx.x - off] : 0;
        __syncthreads();
        buf[threadIdx.x] += t;
        __syncthreads();
    }
    if (i < N_NODES) start[i] = buf[threadIdx.x] - v;   // exclusive
    if (threadIdx.x == 255) sums[blockIdx.x] = buf[255];
}

__global__ __launch_bounds__(512) void k_scan2(int* __restrict__ sums) {
    __shared__ int buf[512];
    int t = threadIdx.x;
    int v = (t < NBLK_SCAN) ? sums[t] : 0;
    buf[t] = v;
    __syncthreads();
    for (int off = 1; off < 512; off <<= 1) {
        int u = (t >= off) ? buf[t - off] : 0;
        __syncthreads();
        buf[t] += u;
        __syncthreads();
    }
    if (t < NBLK_SCAN) sums[t] = buf[t] - v;   // exclusive
}

// finalize start, init cursor, dis = rsqrt(deg+1), and convert W to bf16
__global__ __launch_bounds__(256) void k_scan3(int* __restrict__ start,
                                               int* __restrict__ cursor,
                                               const int* __restrict__ sums,
                                               const int* __restrict__ deg,
                                               float* __restrict__ dis,
                                               const float* __restrict__ w,
                                               __bf16* __restrict__ wb) {
    int i = blockIdx.x * 256 + threadIdx.x;
    if (i < N_NODES) {
        int s = start[i] + sums[blockIdx.x];
        start[i] = s;
        cursor[i] = s;
        dis[i] = rsqrtf((float)deg[i] + 1.0f);
    }
    if (i < D * D) wb[i] = (__bf16)w[i];
}

// ---- pass 2: bucket edges by destination (counting sort) ----
__global__ __launch_bounds__(256) void k_bucket(const int* __restrict__ row,
                                                const int* __restrict__ col,
                                                int* __restrict__ cursor,
                                                int* __restrict__ srcs) {
    int e = blockIdx.x * 256 + threadIdx.x;
    if (e < N_EDGES) {
        int c = col[e];
        int pos = atomicAdd(&cursor[c], 1);
        srcs[pos] = row[e];
    }
}

// ---- pass 3: gather-aggregate, one wave per destination node ----
__global__ __launch_bounds__(256) void k_aggregate(const int* __restrict__ srcs,
                                                   const int* __restrict__ start,
                                                   const int* __restrict__ deg,
                                                   const float* __restrict__ x,
                                                   const float* __restrict__ dis,
                                                   float* __restrict__ out) {
    int node = (blockIdx.x * 256 + threadIdx.x) >> 6;
    int lane = threadIdx.x & 63;
    if (node >= N_NODES) return;
    int s = start[node];
    int n = deg[node];
    float dc = dis[node];
    float2 v0 = ((const float2*)(x + (size_t)node * D))[lane];
    float accx = v0.x * dc * dc;
    float accy = v0.y * dc * dc;

    for (int base = 0; base < n; base += 64) {
        int m = n - base; if (m > 64) m = 64;
        int   src_l = 0;
        float nr_l  = 0.f;
        if (lane < m) {
            src_l = srcs[s + base + lane];
            nr_l  = dis[src_l] * dc;
        }
        int i = 0;
        for (; i + 4 <= m; i += 4) {
            int s0 = __shfl(src_l, i + 0);
            int s1 = __shfl(src_l, i + 1);
            int s2 = __shfl(src_l, i + 2);
            int s3 = __shfl(src_l, i + 3);
            float n0 = __shfl(nr_l, i + 0);
            float n1 = __shfl(nr_l, i + 1);
            float n2 = __shfl(nr_l, i + 2);
            float n3 = __shfl(nr_l, i + 3);
            float2 a0 = ((const float2*)(x + (size_t)s0 * D))[lane];
            float2 a1 = ((const float2*)(x + (size_t)s1 * D))[lane];
            float2 a2 = ((const float2*)(x + (size_t)s2 * D))[lane];
            float2 a3 = ((const float2*)(x + (size_t)s3 * D))[lane];
            accx += a0.x * n0; accy += a0.y * n0;
            accx += a1.x * n1; accy += a1.y * n1;
            accx += a2.x * n2; accy += a2.y * n2;
            accx += a3.x * n3; accy += a3.y * n3;
        }
        for (; i < m; ++i) {
            int   si = __shfl(src_l, i);
            float ni = __shfl(nr_l, i);
            float2 a = ((const float2*)(x + (size_t)si * D))[lane];
            accx += a.x * ni; accy += a.y * ni;
        }
    }
    float2 r; r.x = accx; r.y = accy;
    ((float2*)(out + (size_t)node * D))[lane] = r;
}

// ---- pass 4: in-place out = relu(agg @ W^T + bias) via bf16 MFMA ----
// One wave per 32-row strip; A frags read fp32 from out, cvt to bf16 in-reg.
// All of a thread's loads precede its stores (lockstep wave + waitcnt before
// MFMA), strips are disjoint across waves/blocks -> in-place safe, no LDS.
// Layouts (verified m89/m91): A/B lane holds 8 contiguous k at
// k=(lane>>4)*8; C/D col=lane&15, row=(lane>>4)*4+reg.
__global__ __launch_bounds__(256) void k_transform(const __bf16* __restrict__ wb,
                                                   const float* __restrict__ bias,
                                                   float* __restrict__ out) {
    int wave = threadIdx.x >> 6;
    int lane = threadIdx.x & 63;
    int strip = blockIdx.x * 4 + wave;
    if (strip >= N_STRIPS) return;
    int m0 = strip * 32;
    int l15 = lane & 15;         // A-row / B-col / D-col index
    int kq  = lane >> 4;         // k-quad

    bf16x8 a[2][4];
    #pragma unroll
    for (int mt = 0; mt < 2; ++mt) {
        const float* ap = out + (size_t)(m0 + mt * 16 + l15) * D + kq * 8;
        #pragma unroll
        for (int ks = 0; ks < 4; ++ks) {
            float4 lo = *(const float4*)(ap + ks * 32);
            float4 hi = *(const float4*)(ap + ks * 32 + 4);
            bf16x8 t;
            t[0] = (__bf16)lo.x; t[1] = (__bf16)lo.y;
            t[2] = (__bf16)lo.z; t[3] = (__bf16)lo.w;
            t[4] = (__bf16)hi.x; t[5] = (__bf16)hi.y;
            t[6] = (__bf16)hi.z; t[7] = (__bf16)hi.w;
            a[mt][ks] = t;
        }
    }

    f32x4 acc[2][8] = {};
    #pragma unroll
    for (int ks = 0; ks < 4; ++ks) {
        #pragma unroll
        for (int nt = 0; nt < 8; ++nt) {
            // B[k][n] = W[n][k]: 8 contiguous k from row n of W
            bf16x8 b = *(const bf16x8*)(wb + (size_t)(nt * 16 + l15) * D + ks * 32 + kq * 8);
            acc[0][nt] = __builtin_amdgcn_mfma_f32_16x16x32_bf16(a[0][ks], b, acc[0][nt], 0, 0, 0);
            acc[1][nt] = __builtin_amdgcn_mfma_f32_16x16x32_bf16(a[1][ks], b, acc[1][nt], 0, 0, 0);
        }
    }

    #pragma unroll
    for (int nt = 0; nt < 8; ++nt) {
        int colj = nt * 16 + l15;
        float bj = bias[colj];
        #pragma unroll
        for (int mt = 0; mt < 2; ++mt) {
            #pragma unroll
            for (int r = 0; r < 4; ++r) {
                int rowi = m0 + mt * 16 + kq * 4 + r;
                out[(size_t)rowi * D + colj] = fmaxf(acc[mt][nt][r] + bj, 0.f);
            }
        }
    }
}

extern "C" void kernel_launch(void* const* d_in, const int* in_sizes, int n_in,
                              void* d_out, int out_size, void* d_ws, size_t ws_size,
                              hipStream_t stream) {
    const float* x    = (const float*)d_in[0];
    const int*   ei   = (const int*)d_in[1];    // [2, E]: row then col
    const float* w    = (const float*)d_in[2];
    const float* bias = (const float*)d_in[3];
    float* out = (float*)d_out;

    char* ws = (char*)d_ws;
    int*    deg    = (int*)ws;                ws += N_NODES * 4;
    float*  dis    = (float*)ws;              ws += N_NODES * 4;
    int*    start  = (int*)ws;                ws += N_NODES * 4;
    int*    cursor = (int*)ws;                ws += N_NODES * 4;
    int*    sums   = (int*)ws;                ws += ((NBLK_SCAN + 127) & ~127) * 4;
    __bf16* wb     = (__bf16*)ws;             ws += D * D * 2;
    int*    srcs   = (int*)ws;                // N_EDGES ints

    const int* row = ei;
    const int* col = ei + N_EDGES;

    hipMemsetAsync(deg, 0, N_NODES * sizeof(int), stream);

    k_degree   <<<(N_EDGES + 255) / 256, 256, 0, stream>>>(col, deg);
    k_scan1    <<<NBLK_SCAN, 256, 0, stream>>>(deg, start, sums);
    k_scan2    <<<1, 512, 0, stream>>>(sums);
    k_scan3    <<<NBLK_SCAN, 256, 0, stream>>>(start, cursor, sums, deg, dis, w, wb);
    k_bucket   <<<(N_EDGES + 255) / 256, 256, 0, stream>>>(row, col, cursor, srcs);
    k_aggregate<<<(N_NODES * 64 + 255) / 256, 256, 0, stream>>>(srcs, start, deg, x, dis, out);
    k_transform<<<(N_STRIPS + 3) / 4, 256, 0, stream>>>(wb, bias, out);
}

// Round 5
// 344.993 us; speedup vs baseline: 4.6236x; 1.2570x over previous
//
#include <hip/hip_runtime.h>

#define N_NODES 100000
#define N_EDGES 1600000
#define D 128
#define N_STRIPS (N_NODES / 32)     // 3125

#define BSH   9                     // coarse bucket = col >> 9 (512 nodes/bucket)
#define NBKT  196                   // ceil(100000 / 512)
#define DEPTH 32                    // staging bin depth (records)
#define P1_BLOCKS 128
#define P3_BLOCKS 160               // 10000 edges/block

typedef __bf16 bf16x4 __attribute__((ext_vector_type(4)));
typedef __bf16 bf16x8 __attribute__((ext_vector_type(8)));
typedef float  f32x4  __attribute__((ext_vector_type(4)));

// ---- cast x and W to bf16 (halves gather traffic; same rounding the MFMA
// input conversion applied anyway) ----
__global__ __launch_bounds__(256) void k_cast(const float4* __restrict__ x4,
                                              const float4* __restrict__ w4,
                                              bf16x4* __restrict__ xb4,
                                              bf16x4* __restrict__ wb4) {
    int i = blockIdx.x * 256 + threadIdx.x;      // grid covers N*D/4 exactly
    float4 v = x4[i];
    bf16x4 o;
    o[0] = (__bf16)v.x; o[1] = (__bf16)v.y; o[2] = (__bf16)v.z; o[3] = (__bf16)v.w;
    xb4[i] = o;
    if (i < (D * D) / 4) {
        float4 u = w4[i];
        bf16x4 p;
        p[0] = (__bf16)u.x; p[1] = (__bf16)u.y; p[2] = (__bf16)u.z; p[3] = (__bf16)u.w;
        wb4[i] = p;
    }
}

// ---- P1: coarse histogram (196 buckets) via LDS atomics; 25K global atomics
// total instead of 1.6M ----
__global__ __launch_bounds__(256) void k_chist(const int* __restrict__ col,
                                               int* __restrict__ ghist) {
    __shared__ int lh[NBKT];
    int tid = threadIdx.x;
    for (int b = tid; b < NBKT; b += 256) lh[b] = 0;
    __syncthreads();
    for (int e = blockIdx.x * 256 + tid; e < N_EDGES; e += P1_BLOCKS * 256)
        atomicAdd(&lh[col[e] >> BSH], 1);
    __syncthreads();
    for (int b = tid; b < NBKT; b += 256)
        if (lh[b]) atomicAdd(&ghist[b], lh[b]);
}

// ---- P2: exclusive scan of the 196 coarse counts ----
__global__ __launch_bounds__(256) void k_cscan(const int* __restrict__ ghist,
                                               int* __restrict__ gstart,
                                               int* __restrict__ gcursor) {
    __shared__ int buf[256];
    int t = threadIdx.x;
    int v = (t < NBKT) ? ghist[t] : 0;
    buf[t] = v;
    __syncthreads();
    for (int off = 1; off < 256; off <<= 1) {
        int u = (t >= off) ? buf[t - off] : 0;
        __syncthreads();
        buf[t] += u;
        __syncthreads();
    }
    if (t < NBKT) { int s = buf[t] - v; gstart[t] = s; gcursor[t] = s; }
}

// ---- P3: coarse scatter with LDS-staged 16-record (64 B) flushes.
// rec = (src<<9) | (col&511), 4 B. Global atomics ~130K (vs 1.6M direct). ----
__global__ __launch_bounds__(256) void k_cscatter(const int* __restrict__ row,
                                                  const int* __restrict__ col,
                                                  int* __restrict__ gcursor,
                                                  unsigned* __restrict__ grec) {
    __shared__ unsigned bins[NBKT][DEPTH];
    __shared__ int lcount[NBKT];
    int tid = threadIdx.x;
    for (int b = tid; b < NBKT; b += 256) lcount[b] = 0;
    __syncthreads();
    const int epb = N_EDGES / P3_BLOCKS;          // 10000 exactly
    int e0 = blockIdx.x * epb;
    int e1 = e0 + epb;
    for (int base = e0; base < e1; base += 256) {
        int e = base + tid;
        if (e < e1) {
            int c = col[e];
            unsigned rec = ((unsigned)row[e] << BSH) | (unsigned)(c & ((1 << BSH) - 1));
            int b = c >> BSH;
            int slot = atomicAdd(&lcount[b], 1);
            if (slot < DEPTH) {
                bins[b][slot] = rec;
            } else {                               // rare overflow: direct write
                int pos = atomicAdd(&gcursor[b], 1);
                grec[pos] = rec;
                atomicSub(&lcount[b], 1);
            }
        }
        __syncthreads();
        if (tid < NBKT) {
            int cnt = lcount[tid];
            int n = cnt & ~15;
            if (n) {
                int gp = atomicAdd(&gcursor[tid], n);
                for (int i = 0; i < n; ++i) grec[gp + i] = bins[tid][i];
                int rem = cnt - n;
                for (int i = 0; i < rem; ++i) bins[tid][i] = bins[tid][n + i];
                lcount[tid] = rem;
            }
        }
        __syncthreads();
    }
    if (tid < NBKT) {                              // drain remainders (<16 each)
        int cnt = lcount[tid];
        if (cnt) {
            int gp = atomicAdd(&gcursor[tid], cnt);
            for (int i = 0; i < cnt; ++i) grec[gp + i] = bins[tid][i];
        }
    }
}

// ---- P4: per-bucket fine pass, all atomics in LDS. Emits deg, dis, start,
// and the destination-sorted srcs. Replaces k_degree + 3 scan kernels. ----
__global__ __launch_bounds__(256) void k_fine(const unsigned* __restrict__ grec,
                                              const int* __restrict__ ghist,
                                              const int* __restrict__ gstart,
                                              int* __restrict__ deg,
                                              float* __restrict__ dis,
                                              int* __restrict__ start,
                                              int* __restrict__ srcs) {
    __shared__ int fh[512];
    __shared__ int fstart[512];
    __shared__ int buf[256];
    int b = blockIdx.x;
    int tid = threadIdx.x;
    int cnt = ghist[b];
    int gs = gstart[b];
    fh[tid] = 0; fh[tid + 256] = 0;
    __syncthreads();
    for (int i = tid; i < cnt; i += 256)
        atomicAdd(&fh[grec[gs + i] & 511], 1);
    __syncthreads();
    // two-level exclusive scan over 512 bins (thread owns bins 2t, 2t+1)
    int s0 = fh[2 * tid], s1 = fh[2 * tid + 1];
    int pair = s0 + s1;
    buf[tid] = pair;
    __syncthreads();
    for (int off = 1; off < 256; off <<= 1) {
        int u = (tid >= off) ? buf[tid - off] : 0;
        __syncthreads();
        buf[tid] += u;
        __syncthreads();
    }
    int excl = buf[tid] - pair;
    fstart[2 * tid] = excl;
    fstart[2 * tid + 1] = excl + s0;
    __syncthreads();
    int nb0 = b << BSH;
    #pragma unroll
    for (int k = 0; k < 2; ++k) {
        int bin = tid + k * 256;
        int node = nb0 + bin;
        if (node < N_NODES) {
            int d = fh[bin];
            deg[node] = d;
            dis[node] = rsqrtf((float)d + 1.0f);
            start[node] = gs + fstart[bin];
        }
    }
    __syncthreads();
    fh[tid] = fstart[tid]; fh[tid + 256] = fstart[tid + 256];   // fh -> cursors
    __syncthreads();
    for (int i = tid; i < cnt; i += 256) {
        unsigned r = grec[gs + i];
        int bin = r & 511;
        int pos = atomicAdd(&fh[bin], 1);
        srcs[gs + pos] = (int)(r >> BSH);
    }
}

// ---- gather-aggregate, one wave per destination; bf16 x rows (256 B) ----
__global__ __launch_bounds__(256) void k_aggregate(const int* __restrict__ srcs,
                                                   const int* __restrict__ start,
                                                   const int* __restrict__ deg,
                                                   const __bf16* __restrict__ xb,
                                                   const float* __restrict__ dis,
                                                   float* __restrict__ out) {
    int node = (blockIdx.x * 256 + threadIdx.x) >> 6;
    int lane = threadIdx.x & 63;
    if (node >= N_NODES) return;
    int s = start[node];
    int n = deg[node];
    float dc = dis[node];
    unsigned u0 = ((const unsigned*)(xb + (size_t)node * D))[lane];
    float accx = __uint_as_float(u0 << 16) * dc * dc;
    float accy = __uint_as_float(u0 & 0xFFFF0000u) * dc * dc;

    for (int base = 0; base < n; base += 64) {
        int m = n - base; if (m > 64) m = 64;
        int   src_l = 0;
        float nr_l  = 0.f;
        if (lane < m) {
            src_l = srcs[s + base + lane];
            nr_l  = dis[src_l] * dc;
        }
        int i = 0;
        for (; i + 4 <= m; i += 4) {
            int s0 = __shfl(src_l, i + 0);
            int s1 = __shfl(src_l, i + 1);
            int s2 = __shfl(src_l, i + 2);
            int s3 = __shfl(src_l, i + 3);
            float n0 = __shfl(nr_l, i + 0);
            float n1 = __shfl(nr_l, i + 1);
            float n2 = __shfl(nr_l, i + 2);
            float n3 = __shfl(nr_l, i + 3);
            unsigned a0 = ((const unsigned*)(xb + (size_t)s0 * D))[lane];
            unsigned a1 = ((const unsigned*)(xb + (size_t)s1 * D))[lane];
            unsigned a2 = ((const unsigned*)(xb + (size_t)s2 * D))[lane];
            unsigned a3 = ((const unsigned*)(xb + (size_t)s3 * D))[lane];
            accx += __uint_as_float(a0 << 16) * n0; accy += __uint_as_float(a0 & 0xFFFF0000u) * n0;
            accx += __uint_as_float(a1 << 16) * n1; accy += __uint_as_float(a1 & 0xFFFF0000u) * n1;
            accx += __uint_as_float(a2 << 16) * n2; accy += __uint_as_float(a2 & 0xFFFF0000u) * n2;
            accx += __uint_as_float(a3 << 16) * n3; accy += __uint_as_float(a3 & 0xFFFF0000u) * n3;
        }
        for (; i < m; ++i) {
            int   si = __shfl(src_l, i);
            float ni = __shfl(nr_l, i);
            unsigned a = ((const unsigned*)(xb + (size_t)si * D))[lane];
            accx += __uint_as_float(a << 16) * ni;
            accy += __uint_as_float(a & 0xFFFF0000u) * ni;
        }
    }
    float2 r; r.x = accx; r.y = accy;
    ((float2*)(out + (size_t)node * D))[lane] = r;
}

// ---- in-place out = relu(agg @ W^T + bias) via bf16 MFMA (unchanged R4) ----
__global__ __launch_bounds__(256) void k_transform(const __bf16* __restrict__ wb,
                                                   const float* __restrict__ bias,
                                                   float* __restrict__ out) {
    int wave = threadIdx.x >> 6;
    int lane = threadIdx.x & 63;
    int strip = blockIdx.x * 4 + wave;
    if (strip >= N_STRIPS) return;
    int m0 = strip * 32;
    int l15 = lane & 15;
    int kq  = lane >> 4;

    bf16x8 a[2][4];
    #pragma unroll
    for (int mt = 0; mt < 2; ++mt) {
        const float* ap = out + (size_t)(m0 + mt * 16 + l15) * D + kq * 8;
        #pragma unroll
        for (int ks = 0; ks < 4; ++ks) {
            float4 lo = *(const float4*)(ap + ks * 32);
            float4 hi = *(const float4*)(ap + ks * 32 + 4);
            bf16x8 t;
            t[0] = (__bf16)lo.x; t[1] = (__bf16)lo.y;
            t[2] = (__bf16)lo.z; t[3] = (__bf16)lo.w;
            t[4] = (__bf16)hi.x; t[5] = (__bf16)hi.y;
            t[6] = (__bf16)hi.z; t[7] = (__bf16)hi.w;
            a[mt][ks] = t;
        }
    }

    f32x4 acc[2][8] = {};
    #pragma unroll
    for (int ks = 0; ks < 4; ++ks) {
        #pragma unroll
        for (int nt = 0; nt < 8; ++nt) {
            bf16x8 b = *(const bf16x8*)(wb + (size_t)(nt * 16 + l15) * D + ks * 32 + kq * 8);
            acc[0][nt] = __builtin_amdgcn_mfma_f32_16x16x32_bf16(a[0][ks], b, acc[0][nt], 0, 0, 0);
            acc[1][nt] = __builtin_amdgcn_mfma_f32_16x16x32_bf16(a[1][ks], b, acc[1][nt], 0, 0, 0);
        }
    }

    #pragma unroll
    for (int nt = 0; nt < 8; ++nt) {
        int colj = nt * 16 + l15;
        float bj = bias[colj];
        #pragma unroll
        for (int mt = 0; mt < 2; ++mt) {
            #pragma unroll
            for (int r = 0; r < 4; ++r) {
                int rowi = m0 + mt * 16 + kq * 4 + r;
                out[(size_t)rowi * D + colj] = fmaxf(acc[mt][nt][r] + bj, 0.f);
            }
        }
    }
}

extern "C" void kernel_launch(void* const* d_in, const int* in_sizes, int n_in,
                              void* d_out, int out_size, void* d_ws, size_t ws_size,
                              hipStream_t stream) {
    const float* x    = (const float*)d_in[0];
    const int*   ei   = (const int*)d_in[1];    // [2, E]: row then col
    const float* w    = (const float*)d_in[2];
    const float* bias = (const float*)d_in[3];
    float* out = (float*)d_out;

    char* ws = (char*)d_ws;
    int*      deg     = (int*)ws;             ws += N_NODES * 4;
    float*    dis     = (float*)ws;           ws += N_NODES * 4;
    int*      start   = (int*)ws;             ws += N_NODES * 4;
    int*      ghist   = (int*)ws;             ws += 256 * 4;
    int*      gstart  = (int*)ws;             ws += 256 * 4;
    int*      gcursor = (int*)ws;             ws += 256 * 4;
    __bf16*   wb      = (__bf16*)ws;          ws += D * D * 2;
    unsigned* grec    = (unsigned*)ws;        ws += (size_t)N_EDGES * 4;
    int*      srcs    = (int*)ws;             ws += (size_t)N_EDGES * 4;
    __bf16*   xb      = (__bf16*)ws;          // N_NODES * D * 2 = 25.6 MB

    const int* row = ei;
    const int* col = ei + N_EDGES;

    hipMemsetAsync(ghist, 0, 256 * sizeof(int), stream);

    k_cast     <<<(N_NODES * D / 4) / 256, 256, 0, stream>>>(
                   (const float4*)x, (const float4*)w, (bf16x4*)xb, (bf16x4*)wb);
    k_chist    <<<P1_BLOCKS, 256, 0, stream>>>(col, ghist);
    k_cscan    <<<1, 256, 0, stream>>>(ghist, gstart, gcursor);
    k_cscatter <<<P3_BLOCKS, 256, 0, stream>>>(row, col, gcursor, grec);
    k_fine     <<<NBKT, 256, 0, stream>>>(grec, ghist, gstart, deg, dis, start, srcs);
    k_aggregate<<<(N_NODES * 64 + 255) / 256, 256, 0, stream>>>(srcs, start, deg, xb, dis, out);
    k_transform<<<(N_STRIPS + 3) / 4, 256, 0, stream>>>(wb, bias, out);
}

// Round 6
// 277.803 us; speedup vs baseline: 5.7419x; 1.2419x over previous
//
#include <hip/hip_runtime.h>

#define N_NODES 100000
#define N_EDGES 1600000
#define D 128
#define N_STRIPS (N_NODES / 32)     // 3125

#define BSH   9                     // coarse bucket = col >> 9 (512 nodes/bucket)
#define NBKT  196                   // ceil(100000 / 512)
#define P_BLK 160                   // partition blocks; EPB = 10000 exactly
#define EPB   (N_EDGES / P_BLK)

typedef __bf16 bf16x4 __attribute__((ext_vector_type(4)));
typedef __bf16 bf16x8 __attribute__((ext_vector_type(8)));
typedef float  f32x4  __attribute__((ext_vector_type(4)));

// ---- cast x and W to bf16 ----
__global__ __launch_bounds__(256) void k_cast(const float4* __restrict__ x4,
                                              const float4* __restrict__ w4,
                                              bf16x4* __restrict__ xb4,
                                              bf16x4* __restrict__ wb4) {
    int i = blockIdx.x * 256 + threadIdx.x;      // grid covers N*D/4 exactly
    float4 v = x4[i];
    bf16x4 o;
    o[0] = (__bf16)v.x; o[1] = (__bf16)v.y; o[2] = (__bf16)v.z; o[3] = (__bf16)v.w;
    xb4[i] = o;
    if (i < (D * D) / 4) {
        float4 u = w4[i];
        bf16x4 p;
        p[0] = (__bf16)u.x; p[1] = (__bf16)u.y; p[2] = (__bf16)u.z; p[3] = (__bf16)u.w;
        wb4[i] = p;
    }
}

// ---- P1: per-block coarse histogram -> bhist[k][b] (bucket-major) ----
__global__ __launch_bounds__(256) void k_bhist(const int* __restrict__ col,
                                               int* __restrict__ bhist) {
    __shared__ int lh[NBKT];
    int tid = threadIdx.x, b = blockIdx.x;
    for (int k = tid; k < NBKT; k += 256) lh[k] = 0;
    __syncthreads();
    int e0 = b * EPB;
    for (int e = e0 + tid; e < e0 + EPB; e += 256)
        atomicAdd(&lh[col[e] >> BSH], 1);
    __syncthreads();
    for (int k = tid; k < NBKT; k += 256) bhist[k * P_BLK + b] = lh[k];
}

// ---- P2a: per-bucket exclusive scan over the 160 block counts (in place) ----
__global__ __launch_bounds__(256) void k_bscan(int* __restrict__ bhist,
                                               int* __restrict__ gtot) {
    __shared__ int buf[256];
    int k = blockIdx.x, t = threadIdx.x;
    int v = (t < P_BLK) ? bhist[k * P_BLK + t] : 0;
    buf[t] = v;
    __syncthreads();
    for (int off = 1; off < 256; off <<= 1) {
        int u = (t >= off) ? buf[t - off] : 0;
        __syncthreads();
        buf[t] += u;
        __syncthreads();
    }
    if (t < P_BLK) bhist[k * P_BLK + t] = buf[t] - v;   // exclusive
    if (t == 255) gtot[k] = buf[255];
}

// ---- P2b: exclusive scan of bucket totals -> gstart ----
__global__ __launch_bounds__(256) void k_gscan(const int* __restrict__ gtot,
                                               int* __restrict__ gstart) {
    __shared__ int buf[256];
    int t = threadIdx.x;
    int v = (t < NBKT) ? gtot[t] : 0;
    buf[t] = v;
    __syncthreads();
    for (int off = 1; off < 256; off <<= 1) {
        int u = (t >= off) ? buf[t - off] : 0;
        __syncthreads();
        buf[t] += u;
        __syncthreads();
    }
    if (t < NBKT) gstart[t] = buf[t] - v;
}

// ---- P3: direct scatter; per-block LDS cursors, zero global atomics ----
__global__ __launch_bounds__(256) void k_cscatter(const int* __restrict__ row,
                                                  const int* __restrict__ col,
                                                  const int* __restrict__ bhist,
                                                  const int* __restrict__ gstart,
                                                  unsigned* __restrict__ grec) {
    __shared__ int cur[NBKT];
    int b = blockIdx.x, t = threadIdx.x;
    for (int k = t; k < NBKT; k += 256)
        cur[k] = gstart[k] + bhist[k * P_BLK + b];
    __syncthreads();
    int e0 = b * EPB;
    for (int e = e0 + t; e < e0 + EPB; e += 256) {
        int c = col[e];
        unsigned rec = ((unsigned)row[e] << BSH) | (unsigned)(c & ((1 << BSH) - 1));
        int pos = atomicAdd(&cur[c >> BSH], 1);
        grec[pos] = rec;
    }
}

// ---- P4: per-bucket fine sort in LDS; emits deg/dis/start/srcs ----
__global__ __launch_bounds__(256) void k_fine(const unsigned* __restrict__ grec,
                                              const int* __restrict__ gtot,
                                              const int* __restrict__ gstart,
                                              int* __restrict__ deg,
                                              float* __restrict__ dis,
                                              int* __restrict__ start,
                                              int* __restrict__ srcs) {
    __shared__ int fh[512];
    __shared__ int fstart[512];
    __shared__ int buf[256];
    int b = blockIdx.x;
    int tid = threadIdx.x;
    int cnt = gtot[b];
    int gs = gstart[b];
    fh[tid] = 0; fh[tid + 256] = 0;
    __syncthreads();
    for (int i = tid; i < cnt; i += 256)
        atomicAdd(&fh[grec[gs + i] & 511], 1);
    __syncthreads();
    int s0 = fh[2 * tid], s1 = fh[2 * tid + 1];
    int pair = s0 + s1;
    buf[tid] = pair;
    __syncthreads();
    for (int off = 1; off < 256; off <<= 1) {
        int u = (tid >= off) ? buf[tid - off] : 0;
        __syncthreads();
        buf[tid] += u;
        __syncthreads();
    }
    int excl = buf[tid] - pair;
    fstart[2 * tid] = excl;
    fstart[2 * tid + 1] = excl + s0;
    __syncthreads();
    int nb0 = b << BSH;
    #pragma unroll
    for (int k = 0; k < 2; ++k) {
        int bin = tid + k * 256;
        int node = nb0 + bin;
        if (node < N_NODES) {
            int d = fh[bin];
            deg[node] = d;
            dis[node] = rsqrtf((float)d + 1.0f);
            start[node] = gs + fstart[bin];
        }
    }
    __syncthreads();
    fh[tid] = fstart[tid]; fh[tid + 256] = fstart[tid + 256];   // -> cursors
    __syncthreads();
    for (int i = tid; i < cnt; i += 256) {
        unsigned r = grec[gs + i];
        int bin = r & 511;
        int pos = atomicAdd(&fh[bin], 1);
        srcs[gs + pos] = (int)(r >> BSH);
    }
}

// ---- gather-aggregate, one wave per destination; bf16 x rows (256 B) ----
__global__ __launch_bounds__(256) void k_aggregate(const int* __restrict__ srcs,
                                                   const int* __restrict__ start,
                                                   const int* __restrict__ deg,
                                                   const __bf16* __restrict__ xb,
                                                   const float* __restrict__ dis,
                                                   float* __restrict__ out) {
    int node = (blockIdx.x * 256 + threadIdx.x) >> 6;
    int lane = threadIdx.x & 63;
    if (node >= N_NODES) return;
    int s = start[node];
    int n = deg[node];
    float dc = dis[node];
    unsigned u0 = ((const unsigned*)(xb + (size_t)node * D))[lane];
    float accx = __uint_as_float(u0 << 16) * dc * dc;
    float accy = __uint_as_float(u0 & 0xFFFF0000u) * dc * dc;

    for (int base = 0; base < n; base += 64) {
        int m = n - base; if (m > 64) m = 64;
        int   src_l = 0;
        float nr_l  = 0.f;
        if (lane < m) {
            src_l = srcs[s + base + lane];
            nr_l  = dis[src_l] * dc;
        }
        int i = 0;
        for (; i + 4 <= m; i += 4) {
            int s0 = __shfl(src_l, i + 0);
            int s1 = __shfl(src_l, i + 1);
            int s2 = __shfl(src_l, i + 2);
            int s3 = __shfl(src_l, i + 3);
            float n0 = __shfl(nr_l, i + 0);
            float n1 = __shfl(nr_l, i + 1);
            float n2 = __shfl(nr_l, i + 2);
            float n3 = __shfl(nr_l, i + 3);
            unsigned a0 = ((const unsigned*)(xb + (size_t)s0 * D))[lane];
            unsigned a1 = ((const unsigned*)(xb + (size_t)s1 * D))[lane];
            unsigned a2 = ((const unsigned*)(xb + (size_t)s2 * D))[lane];
            unsigned a3 = ((const unsigned*)(xb + (size_t)s3 * D))[lane];
            accx += __uint_as_float(a0 << 16) * n0; accy += __uint_as_float(a0 & 0xFFFF0000u) * n0;
            accx += __uint_as_float(a1 << 16) * n1; accy += __uint_as_float(a1 & 0xFFFF0000u) * n1;
            accx += __uint_as_float(a2 << 16) * n2; accy += __uint_as_float(a2 & 0xFFFF0000u) * n2;
            accx += __uint_as_float(a3 << 16) * n3; accy += __uint_as_float(a3 & 0xFFFF0000u) * n3;
        }
        for (; i < m; ++i) {
            int   si = __shfl(src_l, i);
            float ni = __shfl(nr_l, i);
            unsigned a = ((const unsigned*)(xb + (size_t)si * D))[lane];
            accx += __uint_as_float(a << 16) * ni;
            accy += __uint_as_float(a & 0xFFFF0000u) * ni;
        }
    }
    float2 r; r.x = accx; r.y = accy;
    ((float2*)(out + (size_t)node * D))[lane] = r;
}

// ---- in-place out = relu(agg @ W^T + bias) via bf16 MFMA ----
__global__ __launch_bounds__(256) void k_transform(const __bf16* __restrict__ wb,
                                                   const float* __restrict__ bias,
                                                   float* __restrict__ out) {
    int wave = threadIdx.x >> 6;
    int lane = threadIdx.x & 63;
    int strip = blockIdx.x * 4 + wave;
    if (strip >= N_STRIPS) return;
    int m0 = strip * 32;
    int l15 = lane & 15;
    int kq  = lane >> 4;

    bf16x8 a[2][4];
    #pragma unroll
    for (int mt = 0; mt < 2; ++mt) {
        const float* ap = out + (size_t)(m0 + mt * 16 + l15) * D + kq * 8;
        #pragma unroll
        for (int ks = 0; ks < 4; ++ks) {
            float4 lo = *(const float4*)(ap + ks * 32);
            float4 hi = *(const float4*)(ap + ks * 32 + 4);
            bf16x8 t;
            t[0] = (__bf16)lo.x; t[1] = (__bf16)lo.y;
            t[2] = (__bf16)lo.z; t[3] = (__bf16)lo.w;
            t[4] = (__bf16)hi.x; t[5] = (__bf16)hi.y;
            t[6] = (__bf16)hi.z; t[7] = (__bf16)hi.w;
            a[mt][ks] = t;
        }
    }

    f32x4 acc[2][8] = {};
    #pragma unroll
    for (int ks = 0; ks < 4; ++ks) {
        #pragma unroll
        for (int nt = 0; nt < 8; ++nt) {
            bf16x8 b = *(const bf16x8*)(wb + (size_t)(nt * 16 + l15) * D + ks * 32 + kq * 8);
            acc[0][nt] = __builtin_amdgcn_mfma_f32_16x16x32_bf16(a[0][ks], b, acc[0][nt], 0, 0, 0);
            acc[1][nt] = __builtin_amdgcn_mfma_f32_16x16x32_bf16(a[1][ks], b, acc[1][nt], 0, 0, 0);
        }
    }

    #pragma unroll
    for (int nt = 0; nt < 8; ++nt) {
        int colj = nt * 16 + l15;
        float bj = bias[colj];
        #pragma unroll
        for (int mt = 0; mt < 2; ++mt) {
            #pragma unroll
            for (int r = 0; r < 4; ++r) {
                int rowi = m0 + mt * 16 + kq * 4 + r;
                out[(size_t)rowi * D + colj] = fmaxf(acc[mt][nt][r] + bj, 0.f);
            }
        }
    }
}

extern "C" void kernel_launch(void* const* d_in, const int* in_sizes, int n_in,
                              void* d_out, int out_size, void* d_ws, size_t ws_size,
                              hipStream_t stream) {
    const float* x    = (const float*)d_in[0];
    const int*   ei   = (const int*)d_in[1];    // [2, E]: row then col
    const float* w    = (const float*)d_in[2];
    const float* bias = (const float*)d_in[3];
    float* out = (float*)d_out;

    char* ws = (char*)d_ws;
    int*      deg    = (int*)ws;              ws += N_NODES * 4;
    float*    dis    = (float*)ws;            ws += N_NODES * 4;
    int*      start  = (int*)ws;              ws += N_NODES * 4;
    int*      bhist  = (int*)ws;              ws += NBKT * P_BLK * 4;
    int*      gtot   = (int*)ws;              ws += 256 * 4;
    int*      gstart = (int*)ws;              ws += 256 * 4;
    __bf16*   wb     = (__bf16*)ws;           ws += D * D * 2;
    unsigned* grec   = (unsigned*)ws;         ws += (size_t)N_EDGES * 4;
    int*      srcs   = (int*)ws;              ws += (size_t)N_EDGES * 4;
    __bf16*   xb     = (__bf16*)ws;           // N_NODES * D * 2 = 25.6 MB

    const int* row = ei;
    const int* col = ei + N_EDGES;

    k_cast     <<<(N_NODES * D / 4) / 256, 256, 0, stream>>>(
                   (const float4*)x, (const float4*)w, (bf16x4*)xb, (bf16x4*)wb);
    k_bhist    <<<P_BLK, 256, 0, stream>>>(col, bhist);
    k_bscan    <<<NBKT, 256, 0, stream>>>(bhist, gtot);
    k_gscan    <<<1, 256, 0, stream>>>(gtot, gstart);
    k_cscatter <<<P_BLK, 256, 0, stream>>>(row, col, bhist, gstart, grec);
    k_fine     <<<NBKT, 256, 0, stream>>>(grec, gtot, gstart, deg, dis, start, srcs);
    k_aggregate<<<(N_NODES * 64 + 255) / 256, 256, 0, stream>>>(srcs, start, deg, xb, dis, out);
    k_transform<<<(N_STRIPS + 3) / 4, 256, 0, stream>>>(wb, bias, out);
}

// Round 7
// 253.269 us; speedup vs baseline: 6.2981x; 1.0969x over previous
//
#include <hip/hip_runtime.h>

#define N_NODES 100000
#define N_EDGES 1600000
#define D 128
#define N_STRIPS (N_NODES / 32)     // 3125

#define BSH   9                     // coarse bucket = col >> 9 (512 nodes/bucket)
#define NBKT  196                   // ceil(100000 / 512)
#define P_BLK 160                   // partition blocks; EPB = 10000 exactly
#define EPB   (N_EDGES / P_BLK)

typedef __bf16 bf16x2 __attribute__((ext_vector_type(2)));
typedef __bf16 bf16x4 __attribute__((ext_vector_type(4)));
typedef __bf16 bf16x8 __attribute__((ext_vector_type(8)));
typedef float  f32x4  __attribute__((ext_vector_type(4)));

// ---- cast x and W to bf16 ----
__global__ __launch_bounds__(256) void k_cast(const float4* __restrict__ x4,
                                              const float4* __restrict__ w4,
                                              bf16x4* __restrict__ xb4,
                                              bf16x4* __restrict__ wb4) {
    int i = blockIdx.x * 256 + threadIdx.x;      // grid covers N*D/4 exactly
    float4 v = x4[i];
    bf16x4 o;
    o[0] = (__bf16)v.x; o[1] = (__bf16)v.y; o[2] = (__bf16)v.z; o[3] = (__bf16)v.w;
    xb4[i] = o;
    if (i < (D * D) / 4) {
        float4 u = w4[i];
        bf16x4 p;
        p[0] = (__bf16)u.x; p[1] = (__bf16)u.y; p[2] = (__bf16)u.z; p[3] = (__bf16)u.w;
        wb4[i] = p;
    }
}

// ---- P1: per-block coarse histogram -> bhist[k][b] (bucket-major) ----
__global__ __launch_bounds__(1024) void k_bhist(const int* __restrict__ col,
                                                int* __restrict__ bhist) {
    __shared__ int lh[NBKT];
    int tid = threadIdx.x, b = blockIdx.x;
    if (tid < NBKT) lh[tid] = 0;
    __syncthreads();
    int e0 = b * EPB;
    for (int e = e0 + tid; e < e0 + EPB; e += 1024)
        atomicAdd(&lh[col[e] >> BSH], 1);
    __syncthreads();
    if (tid < NBKT) bhist[tid * P_BLK + b] = lh[tid];
}

// ---- P2a: per-bucket exclusive scan over the 160 block counts (in place) ----
__global__ __launch_bounds__(256) void k_bscan(int* __restrict__ bhist,
                                               int* __restrict__ gtot) {
    __shared__ int buf[256];
    int k = blockIdx.x, t = threadIdx.x;
    int v = (t < P_BLK) ? bhist[k * P_BLK + t] : 0;
    buf[t] = v;
    __syncthreads();
    for (int off = 1; off < 256; off <<= 1) {
        int u = (t >= off) ? buf[t - off] : 0;
        __syncthreads();
        buf[t] += u;
        __syncthreads();
    }
    if (t < P_BLK) bhist[k * P_BLK + t] = buf[t] - v;   // exclusive
    if (t == 255) gtot[k] = buf[255];
}

// ---- P2b: exclusive scan of bucket totals -> gstart ----
__global__ __launch_bounds__(256) void k_gscan(const int* __restrict__ gtot,
                                               int* __restrict__ gstart) {
    __shared__ int buf[256];
    int t = threadIdx.x;
    int v = (t < NBKT) ? gtot[t] : 0;
    buf[t] = v;
    __syncthreads();
    for (int off = 1; off < 256; off <<= 1) {
        int u = (t >= off) ? buf[t - off] : 0;
        __syncthreads();
        buf[t] += u;
        __syncthreads();
    }
    if (t < NBKT) gstart[t] = buf[t] - v;
}

// ---- P3: direct scatter; per-block LDS cursors, zero global atomics ----
__global__ __launch_bounds__(1024) void k_cscatter(const int* __restrict__ row,
                                                   const int* __restrict__ col,
                                                   const int* __restrict__ bhist,
                                                   const int* __restrict__ gstart,
                                                   unsigned* __restrict__ grec) {
    __shared__ int cur[NBKT];
    int b = blockIdx.x, t = threadIdx.x;
    if (t < NBKT) cur[t] = gstart[t] + bhist[t * P_BLK + b];
    __syncthreads();
    int e0 = b * EPB;
    for (int e = e0 + t; e < e0 + EPB; e += 1024) {
        int c = col[e];
        unsigned rec = ((unsigned)row[e] << BSH) | (unsigned)(c & ((1 << BSH) - 1));
        int pos = atomicAdd(&cur[c >> BSH], 1);
        grec[pos] = rec;
    }
}

// ---- P4: per-bucket fine sort in LDS; emits deg/dis/start/srcs ----
__global__ __launch_bounds__(1024) void k_fine(const unsigned* __restrict__ grec,
                                               const int* __restrict__ gtot,
                                               const int* __restrict__ gstart,
                                               int* __restrict__ deg,
                                               float* __restrict__ dis,
                                               int* __restrict__ start,
                                               int* __restrict__ srcs) {
    __shared__ int fh[512];
    __shared__ int fscan[512];
    int b = blockIdx.x;
    int tid = threadIdx.x;
    int cnt = gtot[b];
    int gs = gstart[b];
    if (tid < 512) fh[tid] = 0;
    __syncthreads();
    for (int i = tid; i < cnt; i += 1024)
        atomicAdd(&fh[grec[gs + i] & 511], 1);
    __syncthreads();
    int v = 0;
    if (tid < 512) { v = fh[tid]; fscan[tid] = v; }
    __syncthreads();
    for (int off = 1; off < 512; off <<= 1) {
        int u = 0;
        if (tid < 512 && tid >= off) u = fscan[tid - off];
        __syncthreads();
        if (tid < 512) fscan[tid] += u;
        __syncthreads();
    }
    if (tid < 512) {
        int excl = fscan[tid] - v;            // exclusive scan value
        int node = (b << BSH) + tid;
        if (node < N_NODES) {
            deg[node] = v;
            dis[node] = rsqrtf((float)v + 1.0f);
            start[node] = gs + excl;
        }
        fh[tid] = excl;                       // -> cursors
    }
    __syncthreads();
    for (int i = tid; i < cnt; i += 1024) {
        unsigned r = grec[gs + i];
        int pos = atomicAdd(&fh[r & 511], 1);
        srcs[gs + pos] = (int)(r >> BSH);
    }
}

// ---- gather-aggregate, one wave per destination; bf16 x rows (256 B);
// edge loop unrolled x8 for MLP ----
__global__ __launch_bounds__(256) void k_aggregate(const int* __restrict__ srcs,
                                                   const int* __restrict__ start,
                                                   const int* __restrict__ deg,
                                                   const __bf16* __restrict__ xb,
                                                   const float* __restrict__ dis,
                                                   float* __restrict__ out) {
    int node = (blockIdx.x * 256 + threadIdx.x) >> 6;
    int lane = threadIdx.x & 63;
    if (node >= N_NODES) return;
    int s = start[node];
    int n = deg[node];
    float dc = dis[node];
    unsigned u0 = ((const unsigned*)(xb + (size_t)node * D))[lane];
    float accx = __uint_as_float(u0 << 16) * dc * dc;
    float accy = __uint_as_float(u0 & 0xFFFF0000u) * dc * dc;

    for (int base = 0; base < n; base += 64) {
        int m = n - base; if (m > 64) m = 64;
        int   src_l = 0;
        float nr_l  = 0.f;
        if (lane < m) {
            src_l = srcs[s + base + lane];
            nr_l  = dis[src_l] * dc;
        }
        int i = 0;
        for (; i + 8 <= m; i += 8) {
            int   sv[8];
            float nv[8];
            unsigned av[8];
            #pragma unroll
            for (int j = 0; j < 8; ++j) {
                sv[j] = __shfl(src_l, i + j);
                nv[j] = __shfl(nr_l, i + j);
            }
            #pragma unroll
            for (int j = 0; j < 8; ++j)
                av[j] = ((const unsigned*)(xb + (size_t)sv[j] * D))[lane];
            #pragma unroll
            for (int j = 0; j < 8; ++j) {
                accx += __uint_as_float(av[j] << 16) * nv[j];
                accy += __uint_as_float(av[j] & 0xFFFF0000u) * nv[j];
            }
        }
        for (; i + 4 <= m; i += 4) {
            int   sv[4];
            float nv[4];
            unsigned av[4];
            #pragma unroll
            for (int j = 0; j < 4; ++j) {
                sv[j] = __shfl(src_l, i + j);
                nv[j] = __shfl(nr_l, i + j);
            }
            #pragma unroll
            for (int j = 0; j < 4; ++j)
                av[j] = ((const unsigned*)(xb + (size_t)sv[j] * D))[lane];
            #pragma unroll
            for (int j = 0; j < 4; ++j) {
                accx += __uint_as_float(av[j] << 16) * nv[j];
                accy += __uint_as_float(av[j] & 0xFFFF0000u) * nv[j];
            }
        }
        for (; i < m; ++i) {
            int   si = __shfl(src_l, i);
            float ni = __shfl(nr_l, i);
            unsigned a = ((const unsigned*)(xb + (size_t)si * D))[lane];
            accx += __uint_as_float(a << 16) * ni;
            accy += __uint_as_float(a & 0xFFFF0000u) * ni;
        }
    }
    float2 r; r.x = accx; r.y = accy;
    ((float2*)(out + (size_t)node * D))[lane] = r;
}

// ---- in-place out = relu(agg @ W^T + bias) via bf16 MFMA ----
__global__ __launch_bounds__(256) void k_transform(const __bf16* __restrict__ wb,
                                                   const float* __restrict__ bias,
                                                   float* __restrict__ out) {
    int wave = threadIdx.x >> 6;
    int lane = threadIdx.x & 63;
    int strip = blockIdx.x * 4 + wave;
    if (strip >= N_STRIPS) return;
    int m0 = strip * 32;
    int l15 = lane & 15;
    int kq  = lane >> 4;

    bf16x8 a[2][4];
    #pragma unroll
    for (int mt = 0; mt < 2; ++mt) {
        const float* ap = out + (size_t)(m0 + mt * 16 + l15) * D + kq * 8;
        #pragma unroll
        for (int ks = 0; ks < 4; ++ks) {
            float4 lo = *(const float4*)(ap + ks * 32);
            float4 hi = *(const float4*)(ap + ks * 32 + 4);
            bf16x8 t;
            t[0] = (__bf16)lo.x; t[1] = (__bf16)lo.y;
            t[2] = (__bf16)lo.z; t[3] = (__bf16)lo.w;
            t[4] = (__bf16)hi.x; t[5] = (__bf16)hi.y;
            t[6] = (__bf16)hi.z; t[7] = (__bf16)hi.w;
            a[mt][ks] = t;
        }
    }

    f32x4 acc[2][8] = {};
    #pragma unroll
    for (int ks = 0; ks < 4; ++ks) {
        #pragma unroll
        for (int nt = 0; nt < 8; ++nt) {
            bf16x8 b = *(const bf16x8*)(wb + (size_t)(nt * 16 + l15) * D + ks * 32 + kq * 8);
            acc[0][nt] = __builtin_amdgcn_mfma_f32_16x16x32_bf16(a[0][ks], b, acc[0][nt], 0, 0, 0);
            acc[1][nt] = __builtin_amdgcn_mfma_f32_16x16x32_bf16(a[1][ks], b, acc[1][nt], 0, 0, 0);
        }
    }

    #pragma unroll
    for (int nt = 0; nt < 8; ++nt) {
        int colj = nt * 16 + l15;
        float bj = bias[colj];
        #pragma unroll
        for (int mt = 0; mt < 2; ++mt) {
            #pragma unroll
            for (int r = 0; r < 4; ++r) {
                int rowi = m0 + mt * 16 + kq * 4 + r;
                out[(size_t)rowi * D + colj] = fmaxf(acc[mt][nt][r] + bj, 0.f);
            }
        }
    }
}

extern "C" void kernel_launch(void* const* d_in, const int* in_sizes, int n_in,
                              void* d_out, int out_size, void* d_ws, size_t ws_size,
                              hipStream_t stream) {
    const float* x    = (const float*)d_in[0];
    const int*   ei   = (const int*)d_in[1];    // [2, E]: row then col
    const float* w    = (const float*)d_in[2];
    const float* bias = (const float*)d_in[3];
    float* out = (float*)d_out;

    char* ws = (char*)d_ws;
    int*      deg    = (int*)ws;              ws += N_NODES * 4;
    float*    dis    = (float*)ws;            ws += N_NODES * 4;
    int*      start  = (int*)ws;              ws += N_NODES * 4;
    int*      bhist  = (int*)ws;              ws += NBKT * P_BLK * 4;
    int*      gtot   = (int*)ws;              ws += 256 * 4;
    int*      gstart = (int*)ws;              ws += 256 * 4;
    __bf16*   wb     = (__bf16*)ws;           ws += D * D * 2;
    unsigned* grec   = (unsigned*)ws;         ws += (size_t)N_EDGES * 4;
    int*      srcs   = (int*)ws;              ws += (size_t)N_EDGES * 4;
    __bf16*   xb     = (__bf16*)ws;           // N_NODES * D * 2 = 25.6 MB

    const int* row = ei;
    const int* col = ei + N_EDGES;

    k_cast     <<<(N_NODES * D / 4) / 256, 256, 0, stream>>>(
                   (const float4*)x, (const float4*)w, (bf16x4*)xb, (bf16x4*)wb);
    k_bhist    <<<P_BLK, 1024, 0, stream>>>(col, bhist);
    k_bscan    <<<NBKT, 256, 0, stream>>>(bhist, gtot);
    k_gscan    <<<1, 256, 0, stream>>>(gtot, gstart);
    k_cscatter <<<P_BLK, 1024, 0, stream>>>(row, col, bhist, gstart, grec);
    k_fine     <<<NBKT, 1024, 0, stream>>>(grec, gtot, gstart, deg, dis, start, srcs);
    k_aggregate<<<(N_NODES * 64 + 255) / 256, 256, 0, stream>>>(srcs, start, deg, xb, dis, out);
    k_transform<<<(N_STRIPS + 3) / 4, 256, 0, stream>>>(wb, bias, out);
}